// Round 1
// baseline (219.079 us; speedup 1.0000x reference)
//
#include <hip/hip_runtime.h>
#include <hip/hip_bf16.h>

#define T_TOK 8192
#define DDIM 1024
#define HDIM 1024
#define NEXP 8
#define KTOP 2
#define NROWS (T_TOK * KTOP)

typedef __attribute__((ext_vector_type(8))) short bf16x8;
typedef __attribute__((ext_vector_type(4))) float f32x4;

__device__ __forceinline__ unsigned short f2bf(float f) {
    unsigned u = __builtin_bit_cast(unsigned, f);
    u += 0x7fffu + ((u >> 16) & 1u);   // RNE
    return (unsigned short)(u >> 16);
}
__device__ __forceinline__ float bf2f(unsigned short h) {
    return __builtin_bit_cast(float, (unsigned)h << 16);
}

// ---------------- prep kernels ----------------

__global__ __launch_bounds__(256) void cvt_bf16_k(const float* __restrict__ in,
                                                  unsigned short* __restrict__ out, int n4) {
    int i = blockIdx.x * 256 + threadIdx.x;
    if (i >= n4) return;
    float4 v = ((const float4*)in)[i];
    ushort4 o;
    o.x = f2bf(v.x); o.y = f2bf(v.y); o.z = f2bf(v.z); o.w = f2bf(v.w);
    ((ushort4*)out)[i] = o;
}

// in: [nmat][R][C] f32  ->  out: [nmat][C][R] bf16
__global__ __launch_bounds__(256) void transpose_cast_k(const float* __restrict__ in,
                                                        unsigned short* __restrict__ out,
                                                        int R, int C) {
    __shared__ unsigned short tile[32][33];
    int m = blockIdx.z;
    const float* src = in + (size_t)m * R * C;
    unsigned short* dst = out + (size_t)m * R * C;
    int c0 = blockIdx.x * 32, r0 = blockIdx.y * 32;
    int tx = threadIdx.x & 31, ty = threadIdx.x >> 5;
#pragma unroll
    for (int i = 0; i < 32; i += 8)
        tile[ty + i][tx] = f2bf(src[(size_t)(r0 + ty + i) * C + c0 + tx]);
    __syncthreads();
#pragma unroll
    for (int i = 0; i < 32; i += 8)
        dst[(size_t)(c0 + ty + i) * R + r0 + tx] = tile[tx][ty + i];
}

// ---------------- GEMM: C = act(A @ B^T + bias) ----------------
// A: bf16 rows (optionally gathered via rowidx), lda elements per row
// Bt: [E][N][K] bf16 (B transposed), biasE: [E][N] f32
// VARIANT 0: Out[r][c] = bf16(acc + bias)
// VARIANT 1: Out[r][c] = bf16(silu(Gin[r][c]) * (acc + bias))

constexpr int BM = 128, BN = 128, BK = 64, LDK = BK + 8;

template <int VARIANT>
__global__ __launch_bounds__(256) void gemm_bt_k(
    const unsigned short* __restrict__ A, const int* __restrict__ rowidx, int lda,
    const unsigned short* __restrict__ Bt, const float* __restrict__ biasE,
    const unsigned short* __restrict__ Gin, unsigned short* __restrict__ Out,
    const int* __restrict__ offsets, int N, int K) {
    __shared__ __align__(16) unsigned short As[BM][LDK];
    __shared__ __align__(16) unsigned short Bs[BN][LDK];

    const int nbn = N / BN;
    int brow = blockIdx.x / nbn, bcol = blockIdx.x % nbn;
    int row0 = brow * BM, col0 = bcol * BN;
    int e = 0;
    while (offsets[e + 1] <= row0) ++e;   // contiguous expert segments

    const unsigned short* Bte = Bt + (size_t)e * N * K;
    const float* bias = biasE + (size_t)e * N;

    int tid = threadIdx.x;
    int lane = tid & 63, wid = tid >> 6;
    int wr = wid >> 1, wc = wid & 1;      // 2x2 wave grid, 64x64 per wave
    int l15 = lane & 15, l4 = lane >> 4;

    int srr = tid >> 3;                   // 0..31 staging row
    int sk8 = (tid & 7) * 8;              // 0..56 staging k (bf16 elems)

    size_t abase[4], bbase[4];
#pragma unroll
    for (int p = 0; p < 4; ++p) {
        int gr = row0 + p * 32 + srr;
        int ar = rowidx ? rowidx[gr] : gr;
        abase[p] = (size_t)ar * lda;
        bbase[p] = (size_t)(col0 + p * 32 + srr) * K;
    }

    f32x4 acc[4][4] = {};

    for (int k0 = 0; k0 < K; k0 += BK) {
#pragma unroll
        for (int p = 0; p < 4; ++p)
            *(uint4*)&As[p * 32 + srr][sk8] = *(const uint4*)(A + abase[p] + k0 + sk8);
#pragma unroll
        for (int p = 0; p < 4; ++p)
            *(uint4*)&Bs[p * 32 + srr][sk8] = *(const uint4*)(Bte + bbase[p] + k0 + sk8);
        __syncthreads();
#pragma unroll
        for (int kk = 0; kk < BK; kk += 32) {
            bf16x8 af[4], bfr[4];
#pragma unroll
            for (int mi = 0; mi < 4; ++mi)
                af[mi] = *(const bf16x8*)&As[wr * 64 + mi * 16 + l15][kk + l4 * 8];
#pragma unroll
            for (int ni = 0; ni < 4; ++ni)
                bfr[ni] = *(const bf16x8*)&Bs[wc * 64 + ni * 16 + l15][kk + l4 * 8];
#pragma unroll
            for (int mi = 0; mi < 4; ++mi)
#pragma unroll
                for (int ni = 0; ni < 4; ++ni)
                    acc[mi][ni] = __builtin_amdgcn_mfma_f32_16x16x32_bf16(
                        af[mi], bfr[ni], acc[mi][ni], 0, 0, 0);
        }
        __syncthreads();
    }

    float bv[4];
#pragma unroll
    for (int ni = 0; ni < 4; ++ni)
        bv[ni] = bias[col0 + wc * 64 + ni * 16 + l15];

#pragma unroll
    for (int mi = 0; mi < 4; ++mi) {
        int orow_b = row0 + wr * 64 + mi * 16 + l4 * 4;
#pragma unroll
        for (int ni = 0; ni < 4; ++ni) {
            int ocol = col0 + wc * 64 + ni * 16 + l15;
#pragma unroll
            for (int q = 0; q < 4; ++q) {
                size_t oidx = (size_t)(orow_b + q) * N + ocol;
                float v = acc[mi][ni][q] + bv[ni];
                if (VARIANT == 1) {
                    float g = bf2f(Gin[oidx]);
                    float s = g / (1.0f + __expf(-g));
                    v = s * v;
                }
                Out[oidx] = f2bf(v);
            }
        }
    }
}

// ---------------- combine ----------------

__global__ __launch_bounds__(256) void combine_k(
    const unsigned short* __restrict__ Y, const int* __restrict__ rev,
    const float* __restrict__ gates, const int* __restrict__ gidx,
    float* __restrict__ out) {
    int t = blockIdx.x;
    int r0 = rev[2 * t], r1 = rev[2 * t + 1];
    float g0 = gates[gidx[2 * t]], g1 = gates[gidx[2 * t + 1]];
    const unsigned short* y0 = Y + (size_t)r0 * DDIM;
    const unsigned short* y1 = Y + (size_t)r1 * DDIM;
    int d = threadIdx.x * 4;
    ushort4 a = *(const ushort4*)(y0 + d);
    ushort4 b = *(const ushort4*)(y1 + d);
    float4 r;
    r.x = g0 * bf2f(a.x) + g1 * bf2f(b.x);
    r.y = g0 * bf2f(a.y) + g1 * bf2f(b.y);
    r.z = g0 * bf2f(a.z) + g1 * bf2f(b.z);
    r.w = g0 * bf2f(a.w) + g1 * bf2f(b.w);
    *(float4*)(out + (size_t)t * DDIM + d) = r;
}

// ---------------- launch ----------------

extern "C" void kernel_launch(void* const* d_in, const int* in_sizes, int n_in,
                              void* d_out, int out_size, void* d_ws, size_t ws_size,
                              hipStream_t stream) {
    const int* offsets = (const int*)d_in[0];
    const float* jagged = (const float*)d_in[1];
    const float* weight = (const float*)d_in[2];
    const float* bias = (const float*)d_in[3];
    const int* index = (const int*)d_in[4];
    const float* weight_p = (const float*)d_in[5];
    const float* weight_out = (const float*)d_in[6];
    const int* rev = (const int*)d_in[7];
    const float* gates = (const float*)d_in[8];
    const int* gidx = (const int*)d_in[9];
    const float* bias_p = (const float*)d_in[10];
    const float* bias_out = (const float*)d_in[11];
    float* out = (float*)d_out;

    char* w = (char*)d_ws;
    unsigned short* jag_bf = (unsigned short*)w; w += (size_t)T_TOK * DDIM * 2;   // 16MB
    unsigned short* W1t    = (unsigned short*)w; w += (size_t)NEXP * DDIM * HDIM * 2; // 16MB
    unsigned short* Wpt    = (unsigned short*)w; w += (size_t)NEXP * DDIM * HDIM * 2; // 16MB
    unsigned short* Wot    = (unsigned short*)w; w += (size_t)NEXP * HDIM * DDIM * 2; // 16MB
    unsigned short* g_ws   = (unsigned short*)w; w += (size_t)NROWS * HDIM * 2;   // 32MB
    unsigned short* h_ws   = (unsigned short*)w; w += (size_t)NROWS * HDIM * 2;   // 32MB
    unsigned short* y_ws   = g_ws;  // g dead after GEMM-u epilogue; reuse for y

    // prep: bf16 casts + weight transposes (B^T layout for contiguous MFMA frags)
    cvt_bf16_k<<<(T_TOK * DDIM / 4 + 255) / 256, 256, 0, stream>>>(jagged, jag_bf, T_TOK * DDIM / 4);
    transpose_cast_k<<<dim3(HDIM / 32, DDIM / 32, NEXP), 256, 0, stream>>>(weight, W1t, DDIM, HDIM);
    transpose_cast_k<<<dim3(HDIM / 32, DDIM / 32, NEXP), 256, 0, stream>>>(weight_p, Wpt, DDIM, HDIM);
    transpose_cast_k<<<dim3(DDIM / 32, HDIM / 32, NEXP), 256, 0, stream>>>(weight_out, Wot, HDIM, DDIM);

    // g = gather(x) @ W + b
    int grid1 = (NROWS / BM) * (HDIM / BN);
    gemm_bt_k<0><<<grid1, 256, 0, stream>>>(jag_bf, index, DDIM, W1t, bias, nullptr, g_ws,
                                            offsets, HDIM, DDIM);
    // h = silu(g) * (gather(x) @ Wp + bp)
    gemm_bt_k<1><<<grid1, 256, 0, stream>>>(jag_bf, index, DDIM, Wpt, bias_p, g_ws, h_ws,
                                            offsets, HDIM, DDIM);
    // y = h @ Wout + bout
    int grid3 = (NROWS / BM) * (DDIM / BN);
    gemm_bt_k<0><<<grid3, 256, 0, stream>>>(h_ws, nullptr, HDIM, Wot, bias_out, nullptr, y_ws,
                                            offsets, DDIM, HDIM);
    // out[t] = sum_k gates[gidx[t,k]] * y[rev[t,k]]
    combine_k<<<T_TOK, 256, 0, stream>>>(y_ws, rev, gates, gidx, out);
}